// Round 15
// baseline (219.677 us; speedup 1.0000x reference)
//
#include <hip/hip_runtime.h>

#define N_ 4
#define C_ 64
#define H_ 224
#define W_ 224
#define HW_ (H_ * W_)        /* 50176 */
#define CHW_ (C_ * HW_)      /* 3211264 */
#define TOT_ (N_ * CHW_)     /* 12845056 */

typedef __bf16 bf8 __attribute__((ext_vector_type(8)));
typedef float  f4v __attribute__((ext_vector_type(4)));
typedef unsigned short u16;

__device__ __forceinline__ float relu_(float v) { return fmaxf(v, 0.f); }
__device__ __forceinline__ u16 f2bf(float f) {
    unsigned u = __builtin_bit_cast(unsigned, f);
    return (u16)((u + 0x7FFFu + ((u >> 16) & 1u)) >> 16);
}
__device__ __forceinline__ float bf2f(u16 h) {
    unsigned u = ((unsigned)h) << 16;
    return __builtin_bit_cast(float, u);
}
__device__ __forceinline__ float bflo(unsigned u) {
    return __builtin_bit_cast(float, u << 16);
}
__device__ __forceinline__ float bfhi(unsigned u) {
    return __builtin_bit_cast(float, u & 0xFFFF0000u);
}

// async 16B global->LDS (LDS dest = wave-uniform base + lane*16)
__device__ __forceinline__ void gl_lds16(const void* g, void* l) {
    __builtin_amdgcn_global_load_lds(
        (const __attribute__((address_space(1))) void*)g,
        (__attribute__((address_space(3))) void*)l, 16, 0, 0);
}

// Wpre[sel][tap][o][k] bf16 <- wd[o][k][tap]   (B-operand ready: o rows, k contiguous)
__global__ __launch_bounds__(256) void prep_w(
    const float* __restrict__ wd1, const float* __restrict__ wd2,
    u16* __restrict__ wpre)
{
    int i = blockIdx.x * 256 + threadIdx.x;
    if (i >= 73728) return;
    int sel = i >= 36864;
    int r   = i - sel * 36864;
    int tap = r >> 12;
    int r2  = r & 4095;
    int o   = r2 >> 6, k = r2 & 63;
    const float* ws = sel ? wd2 : wd1;
    wpre[i] = f2bf(ws[o * 576 + k * 9 + tap]);
}

// Layer-1 T pass: block = 32-px row strip x 64 ch; thread = 4 px x 2 ch.
// Wide float4 row loads (deep ILP), u32-packed LDS transpose, full-line NHWC
// writes. 1D grid with bijective XCD chunk swizzle (6272 = 8 x 784).
__global__ __launch_bounds__(256) void tpass1(
    const float* __restrict__ x, const float* __restrict__ wsh,
    u16* __restrict__ th)
{
    __shared__ unsigned TL[32][36];   // [px][ch-pair], stride 36 words

    float wk[9];
#pragma unroll
    for (int k = 0; k < 9; ++k) wk[k] = wsh[k];
    const float wc1 = wk[4] + 1.f;

    const int orig = blockIdx.x;                  // nwg = 6272 = 8*784
    const int swz  = (orig & 7) * 784 + (orig >> 3);
    const int n    = swz / 1568;
    const int rem  = swz - n * 1568;
    const int row  = rem / 7;
    const int strip = rem - row * 7;

    const int tid = threadIdx.x;
    const int qd = tid & 7;          // pixel quad within strip
    const int c2 = tid >> 3;         // channel pair 0..31
    const int w0 = strip * 32 + qd * 4;
    const bool ym = row > 0, yp = row < H_ - 1;
    const bool xm = w0 > 0, xp = w0 + 4 < W_;

    float tq[2][4];
#pragma unroll
    for (int s = 0; s < 2; ++s) {
        const int ch = c2 * 2 + s;
        const float* bp = x + (size_t)n * CHW_ + (size_t)ch * HW_ + row * W_ + w0;

        float m0[4] = {0,0,0,0}, m1[4], m2[4] = {0,0,0,0};
        float l0 = 0.f, r0 = 0.f, l1 = 0.f, r1 = 0.f, l2 = 0.f, r2 = 0.f;
        if (ym) {
            float4 v = *(const float4*)(bp - W_);
            m0[0] = v.x; m0[1] = v.y; m0[2] = v.z; m0[3] = v.w;
            if (xm) l0 = bp[-W_ - 1];
            if (xp) r0 = bp[-W_ + 4];
        }
        {
            float4 v = *(const float4*)bp;
            m1[0] = v.x; m1[1] = v.y; m1[2] = v.z; m1[3] = v.w;
            if (xm) l1 = bp[-1];
            if (xp) r1 = bp[4];
        }
        if (yp) {
            float4 v = *(const float4*)(bp + W_);
            m2[0] = v.x; m2[1] = v.y; m2[2] = v.z; m2[3] = v.w;
            if (xm) l2 = bp[W_ - 1];
            if (xp) r2 = bp[W_ + 4];
        }
#pragma unroll
        for (int j = 0; j < 4; ++j) {
            float a0 = (j == 0) ? l0 : m0[j - 1];
            float a2 = (j == 3) ? r0 : m0[j + 1];
            float b0 = (j == 0) ? l1 : m1[j - 1];
            float b2 = (j == 3) ? r1 : m1[j + 1];
            float c0 = (j == 0) ? l2 : m2[j - 1];
            float c2v = (j == 3) ? r2 : m2[j + 1];
            float t = wc1 * m1[j];
            t = fmaf(wk[0], a0,    t);
            t = fmaf(wk[1], m0[j], t);
            t = fmaf(wk[2], a2,    t);
            t = fmaf(wk[3], b0,    t);
            t = fmaf(wk[5], b2,    t);
            t = fmaf(wk[6], c0,    t);
            t = fmaf(wk[7], m2[j], t);
            t = fmaf(wk[8], c2v,   t);
            tq[s][j] = t;
        }
    }
#pragma unroll
    for (int j = 0; j < 4; ++j)
        TL[qd * 4 + j][c2] = (unsigned)f2bf(tq[0][j]) | ((unsigned)f2bf(tq[1][j]) << 16);
    __syncthreads();

    const int px = tid >> 3, s = tid & 7;
    uint4 v = *(const uint4*)&TL[px][s * 4];
    *(uint4*)(th + (size_t)(n * HW_ + row * W_ + strip * 32 + px) * 64 + s * 8) = v;
}

// Layer-2 T pass on NHWC bf16, v2: thread = 4 consecutive px x 8 ch.
// Per row: 6 uint4 loads (4 px + 2 halo), each value unpacked+normalized ONCE,
// scattered into t[4][8] (static indices). Grid 1568 = 8 x 196, XCD-banded.
__global__ __launch_bounds__(256) void tpass2(
    const u16* __restrict__ inh, const float* __restrict__ wsh,
    const float* __restrict__ raw, const float* __restrict__ gamma,
    const float* __restrict__ beta, u16* __restrict__ th)
{
    __shared__ float SS[128];
    const int tid = threadIdx.x;
    if (tid < 64) {
        const float cnt = (float)(N_ * HW_);
        float mean = raw[tid] / cnt;
        float var  = raw[64 + tid] / cnt - mean * mean;
        float inv  = rsqrtf(var + 1e-5f);
        float scv  = gamma[tid] * inv;
        SS[tid]      = scv;
        SS[64 + tid] = fmaf(-scv, mean, beta[tid]);
    }
    __syncthreads();

    float wk[9];
#pragma unroll
    for (int k = 0; k < 9; ++k) wk[k] = wsh[k];
    const float wc1 = wk[4] + 1.f;

    const int orig = blockIdx.x;                 // 1568 = 8 * 196
    const int swz  = (orig & 7) * 196 + (orig >> 3);
    const int pp4  = swz * 32 + (tid >> 3);      // global 4-px group
    const int s    = tid & 7;
    const int c0   = s * 8;

    float sc[8], sh[8];
#pragma unroll
    for (int j = 0; j < 8; ++j) { sc[j] = SS[c0 + j]; sh[j] = SS[64 + c0 + j]; }

    const int p0  = pp4 * 4;                     // global pixel index (n*HW + pix)
    const int pix = p0 % HW_;
    const int gh  = pix / W_;
    const int gw  = pix - gh * W_;               // multiple of 4
    const bool ym = gh > 0, yp = gh < H_ - 1;
    const bool xm = gw > 0, xp = gw < W_ - 4;

    float t[4][8];
#pragma unroll
    for (int j = 0; j < 4; ++j)
#pragma unroll
        for (int c = 0; c < 8; ++c) t[j][c] = 0.f;

#pragma unroll
    for (int r = 0; r < 3; ++r) {
        if (r == 0 && !ym) continue;
        if (r == 2 && !yp) continue;
        const float w0 = wk[r * 3];
        const float w1 = (r == 1) ? wc1 : wk[r * 3 + 1];
        const float w2 = wk[r * 3 + 2];
        const u16* rb = inh + ((size_t)(p0 + (r - 1) * W_) * 64 + c0);

        uint4 L[6];
        bool lv[6];
#pragma unroll
        for (int m = 0; m < 6; ++m) {
            lv[m] = (m == 0) ? xm : ((m == 5) ? xp : true);
            if (lv[m]) L[m] = *(const uint4*)(rb + (m - 1) * 64);
        }
#pragma unroll
        for (int m = 0; m < 6; ++m) {
            if (!lv[m]) continue;
            unsigned wd_[4] = { L[m].x, L[m].y, L[m].z, L[m].w };
            float val[8];
#pragma unroll
            for (int q = 0; q < 4; ++q) {
                val[2 * q]     = relu_(fmaf(sc[2 * q],     bflo(wd_[q]), sh[2 * q]));
                val[2 * q + 1] = relu_(fmaf(sc[2 * q + 1], bfhi(wd_[q]), sh[2 * q + 1]));
            }
            const int jlo = (m < 2) ? 0 : m - 2;
            const int jhi = (m < 3) ? m : 3;
#pragma unroll
            for (int j = jlo; j <= jhi; ++j) {
                const int dc = m - j;
                const float wgt = (dc == 0) ? w0 : ((dc == 1) ? w1 : w2);
#pragma unroll
                for (int c = 0; c < 8; ++c)
                    t[j][c] = fmaf(wgt, val[c], t[j][c]);
            }
        }
    }

#pragma unroll
    for (int j = 0; j < 4; ++j) {
        uint4 pk;
        pk.x = (unsigned)f2bf(t[j][0]) | ((unsigned)f2bf(t[j][1]) << 16);
        pk.y = (unsigned)f2bf(t[j][2]) | ((unsigned)f2bf(t[j][3]) << 16);
        pk.z = (unsigned)f2bf(t[j][4]) | ((unsigned)f2bf(t[j][5]) << 16);
        pk.w = (unsigned)f2bf(t[j][6]) | ((unsigned)f2bf(t[j][7]) << 16);
        *(uint4*)(th + (size_t)(p0 + j) * 64 + c0) = pk;
    }
}

// Dense 3x3 conv as implicit GEMM over NHWC bf16 T. R10/R14 body structure
// UNCHANGED (B[18] hoisted, mf-outer, gl_lds staging w/ source-side swizzle,
// same epilogue); tile TH 8->4 for occupancy: LDS 27KB + acc[8] (32 AGPR)
// fits 4 blocks/CU at launch_bounds(256,4) (84+32=116 < 128 reg cap).
// LAYER 1: resid = x fp32 NCHW, dst = o1h bf16 NHWC.
// LAYER 2: resid = relu(bn1(o1h)), stats from raw1 in-block; dst = o2 fp32 NCHW.
template<int LAYER>
__global__ __launch_bounds__(256, 4) void conv_mfma(
    const u16* __restrict__ th, const u16* __restrict__ wpre,
    const float* __restrict__ bd,
    const float* __restrict__ rawin, const float* __restrict__ gamma,
    const float* __restrict__ beta,
    const float* __restrict__ resx, const u16* __restrict__ reso,
    const u16* __restrict__ zp,
    u16* __restrict__ dsth, float* __restrict__ dstf,
    float* __restrict__ raw)
{
    __shared__ __align__(16) char TlB[204 * 128];   // 26112 B (6x34 halo rows)
    __shared__ float Sr[128];
    __shared__ float SS[128];

    const int tid = threadIdx.x;
    // XCD band swizzle: 1568 = 8 * 196; XCD k owns a contiguous 112-row band
    // of image n=k/2 (matches tpass banding for cross-kernel L2 reuse).
    const int orig = blockIdx.x;
    const int swz  = (orig & 7) * 196 + (orig >> 3);
    const int wx   = swz % 7;
    const int t_   = swz / 7;            // n*56 + hy
    const int n    = t_ / 56;
    const int hy   = t_ - n * 56;
    const int h0 = hy * 4, w0 = wx * 32;

    const int lane = tid & 63, wg = tid >> 6;
    const int l15 = lane & 15, lg = lane >> 4;
    const int o = wg * 16 + l15;

    // Stage T halo (34x6 pixels x 128B) via global_load_lds FIRST:
    // LDS dest linear (wave base + lane*16); XOR swizzle applied to the
    // GLOBAL source address (involution; read side unchanged). OOB -> zero page.
#pragma unroll
    for (int it = 0; it < 7; ++it) {
        const int f = it * 256 + tid;
        if (f < 1632) {
            const int pix = f >> 3, s = f & 7;
            const int hr = pix / 34, wc = pix - hr * 34;
            const int gh = h0 - 1 + hr, gw = w0 - 1 + wc;
            const u16* src = zp;
            if ((unsigned)gh < (unsigned)H_ && (unsigned)gw < (unsigned)W_)
                src = th + (size_t)(n * HW_ + gh * W_ + gw) * 64 +
                      ((s * 8) ^ ((pix & 7) << 3));
            gl_lds16(src, TlB + (size_t)(it * 256 + (tid & 192)) * 16);
        }
    }

    if (LAYER == 2 && tid < 64) {
        const float cnt = (float)(N_ * HW_);
        float mean = rawin[tid] / cnt;
        float var  = rawin[64 + tid] / cnt - mean * mean;
        float inv  = rsqrtf(var + 1e-5f);
        float scv  = gamma[tid] * inv;
        SS[tid]      = scv;
        SS[64 + tid] = fmaf(-scv, mean, beta[tid]);
    }

    // B fragments: [tap][cc] -> 18 x bf16x8 in registers (L2-cached source),
    // issued in the staging DMA's shadow.
    bf8 B[18];
#pragma unroll
    for (int tap = 0; tap < 9; ++tap)
#pragma unroll
        for (int cc = 0; cc < 2; ++cc)
            B[tap * 2 + cc] = *(const bf8*)(wpre + ((tap * 64 + o) * 64 + cc * 32 + lg * 8));

    __syncthreads();

    f4v acc[8];
#pragma unroll
    for (int mf = 0; mf < 8; ++mf) acc[mf] = (f4v){0.f, 0.f, 0.f, 0.f};

#pragma unroll
    for (int mf = 0; mf < 8; ++mf) {
        const int h = mf >> 1, half = mf & 1;
#pragma unroll
        for (int tap = 0; tap < 9; ++tap) {
            const int dr = tap / 3, dc = tap - dr * 3;
            const int hp = (h + dr) * 34 + half * 16 + dc + l15;
#pragma unroll
            for (int cc = 0; cc < 2; ++cc) {
                const bf8 A = *(const bf8*)(TlB + hp * 128 +
                                            ((cc * 64 + lg * 16) ^ ((hp & 7) << 4)));
                acc[mf] = __builtin_amdgcn_mfma_f32_16x16x32_bf16(
                    A, B[tap * 2 + cc], acc[mf], 0, 0, 0);
            }
        }
    }

    // Epilogue: bias + residual + store + per-channel stats
    const float bv = bd[o];
    float scO = 1.f, shO = 0.f;
    if (LAYER == 2) { scO = SS[o]; shO = SS[64 + o]; }
    float ps1 = 0.f, ps2 = 0.f;
#pragma unroll
    for (int mf = 0; mf < 8; ++mf) {
        const int h = h0 + (mf >> 1);
        const int w = w0 + (mf & 1) * 16 + lg * 4;
        const int ppix = n * HW_ + h * W_ + w;
        float vo[4];
        if (LAYER == 1) {
            const float4 rx = *(const float4*)(resx + (size_t)n * CHW_ + (size_t)o * HW_ + h * W_ + w);
            vo[0] = acc[mf][0] + bv + rx.x;
            vo[1] = acc[mf][1] + bv + rx.y;
            vo[2] = acc[mf][2] + bv + rx.z;
            vo[3] = acc[mf][3] + bv + rx.w;
#pragma unroll
            for (int r = 0; r < 4; ++r)
                dsth[(size_t)(ppix + r) * 64 + o] = f2bf(vo[r]);
        } else {
#pragma unroll
            for (int r = 0; r < 4; ++r) {
                float n1 = relu_(fmaf(scO, bf2f(reso[(size_t)(ppix + r) * 64 + o]), shO));
                vo[r] = acc[mf][r] + bv + n1;
            }
            float4 st = { vo[0], vo[1], vo[2], vo[3] };
            *(float4*)(dstf + (size_t)n * CHW_ + (size_t)o * HW_ + h * W_ + w) = st;
        }
        ps1 += (vo[0] + vo[1]) + (vo[2] + vo[3]);
        ps2 += fmaf(vo[0], vo[0], fmaf(vo[1], vo[1], fmaf(vo[2], vo[2], vo[3] * vo[3])));
    }
    ps1 += __shfl_xor(ps1, 16); ps1 += __shfl_xor(ps1, 32);
    ps2 += __shfl_xor(ps2, 16); ps2 += __shfl_xor(ps2, 32);
    if (lane < 16) { Sr[o] = ps1; Sr[64 + o] = ps2; }
    __syncthreads();
    if (tid < 128) atomicAdd(&raw[tid], Sr[tid]);
}

// io = relu(bn2(io)) + x, bn2 scale/shift computed in-block from raw2 sums.
__global__ __launch_bounds__(256) void final_k(
    float4* io, const float* __restrict__ raw, const float* __restrict__ gamma,
    const float* __restrict__ beta, const float4* __restrict__ x)
{
    __shared__ float SS[128];
    if (threadIdx.x < 64) {
        const int c = threadIdx.x;
        const float cnt = (float)(N_ * HW_);
        float mean = raw[c] / cnt;
        float var  = raw[64 + c] / cnt - mean * mean;
        float inv  = rsqrtf(var + 1e-5f);
        float scv  = gamma[c] * inv;
        SS[c]      = scv;
        SS[64 + c] = fmaf(-scv, mean, beta[c]);
    }
    __syncthreads();

    const int nq = TOT_ / 4;
    for (int i = blockIdx.x * 256 + threadIdx.x; i < nq; i += gridDim.x * 256) {
        int c = (i / (HW_ / 4)) & 63;
        float sc = SS[c], sh = SS[64 + c];
        float4 v = io[i], xx = x[i];
        float4 rr;
        rr.x = relu_(fmaf(sc, v.x, sh)) + xx.x;
        rr.y = relu_(fmaf(sc, v.y, sh)) + xx.y;
        rr.z = relu_(fmaf(sc, v.z, sh)) + xx.z;
        rr.w = relu_(fmaf(sc, v.w, sh)) + xx.w;
        io[i] = rr;
    }
}

extern "C" void kernel_launch(void* const* d_in, const int* in_sizes, int n_in,
                              void* d_out, int out_size, void* d_ws, size_t ws_size,
                              hipStream_t stream)
{
    const float* x    = (const float*)d_in[0];
    const float* wsh1 = (const float*)d_in[1];
    const float* wd1  = (const float*)d_in[2];
    const float* bd1  = (const float*)d_in[3];
    const float* wsh2 = (const float*)d_in[4];
    const float* wd2  = (const float*)d_in[5];
    const float* bd2  = (const float*)d_in[6];
    const float* g1   = (const float*)d_in[7];
    const float* be1  = (const float*)d_in[8];
    const float* g2   = (const float*)d_in[9];
    const float* be2  = (const float*)d_in[10];

    float* out = (float*)d_out;
    u16* Th   = (u16*)d_ws;            // TOT_ u16  (T tensor NHWC, both layers)
    u16* O1h  = Th + TOT_;             // TOT_ u16  (o1 bf16 NHWC)
    u16* Wpre = O1h + TOT_;            // 73728 u16
    float* raw1 = (float*)(Wpre + 73728);  // 128
    float* raw2 = raw1 + 128;              // 128
    u16*   zp   = (u16*)(raw2 + 128);      // 64 u16 zero page (OOB halo src)

    // zero raw1+raw2+zp in one async memset (graph-capture safe)
    hipMemsetAsync(raw1, 0, 256 * sizeof(float) + 128, stream);
    prep_w<<<288, 256, 0, stream>>>(wd1, wd2, Wpre);

    const int tgrid = N_ * H_ * 7;     // 6272 = 8 * 784 (swizzle-divisible)
    const int cgrid = 1568;            // 8 * 196, 1D XCD-banded (TH=4 tiles)
    const int t2grid = 1568;           // 8 * 196, XCD-banded (matches conv bands)

    // T1 = dw(x) + x  (NHWC bf16, fused transpose from fp32 NCHW)
    tpass1<<<tgrid, 256, 0, stream>>>(x, wsh1, Th);
    // o1 = conv(T1) + b1 + x -> o1h (bf16 NHWC); raw1 stats
    conv_mfma<1><<<cgrid, 256, 0, stream>>>(Th, Wpre, bd1,
                                            nullptr, nullptr, nullptr,
                                            x, nullptr, zp, O1h, nullptr, raw1);
    // T2 = dw(n1) + n1, n1 = relu(bn1(o1h)); bn1 stats folded in
    tpass2<<<t2grid, 256, 0, stream>>>(O1h, wsh2, raw1, g1, be1, Th);
    // o2 = conv(T2) + b2 + n1 -> d_out (fp32 NCHW); raw2 stats
    conv_mfma<2><<<cgrid, 256, 0, stream>>>(Th, Wpre + 36864, bd2,
                                            raw1, g1, be1,
                                            nullptr, O1h, zp, nullptr, out, raw2);
    // out = relu(bn2(o2)) + x; bn2 stats folded in
    final_k<<<2048, 256, 0, stream>>>((float4*)out, raw2, g2, be2, (const float4*)x);
}

// Round 16
// 163.218 us; speedup vs baseline: 1.3459x; 1.3459x over previous
//
#include <hip/hip_runtime.h>

#define N_ 4
#define C_ 64
#define H_ 224
#define W_ 224
#define HW_ (H_ * W_)        /* 50176 */
#define CHW_ (C_ * HW_)      /* 3211264 */
#define TOT_ (N_ * CHW_)     /* 12845056 */

typedef __bf16 bf8 __attribute__((ext_vector_type(8)));
typedef float  f4v __attribute__((ext_vector_type(4)));
typedef unsigned short u16;

__device__ __forceinline__ float relu_(float v) { return fmaxf(v, 0.f); }
__device__ __forceinline__ u16 f2bf(float f) {
    unsigned u = __builtin_bit_cast(unsigned, f);
    return (u16)((u + 0x7FFFu + ((u >> 16) & 1u)) >> 16);
}
__device__ __forceinline__ float bf2f(u16 h) {
    unsigned u = ((unsigned)h) << 16;
    return __builtin_bit_cast(float, u);
}
__device__ __forceinline__ float bflo(unsigned u) {
    return __builtin_bit_cast(float, u << 16);
}
__device__ __forceinline__ float bfhi(unsigned u) {
    return __builtin_bit_cast(float, u & 0xFFFF0000u);
}

// async 16B global->LDS (LDS dest = wave-uniform base + lane*16)
__device__ __forceinline__ void gl_lds16(const void* g, void* l) {
    __builtin_amdgcn_global_load_lds(
        (const __attribute__((address_space(1))) void*)g,
        (__attribute__((address_space(3))) void*)l, 16, 0, 0);
}

// Wpre[sel][tap][o][k] bf16 <- wd[o][k][tap]   (B-operand ready: o rows, k contiguous)
__global__ __launch_bounds__(256) void prep_w(
    const float* __restrict__ wd1, const float* __restrict__ wd2,
    u16* __restrict__ wpre)
{
    int i = blockIdx.x * 256 + threadIdx.x;
    if (i >= 73728) return;
    int sel = i >= 36864;
    int r   = i - sel * 36864;
    int tap = r >> 12;
    int r2  = r & 4095;
    int o   = r2 >> 6, k = r2 & 63;
    const float* ws = sel ? wd2 : wd1;
    wpre[i] = f2bf(ws[o * 576 + k * 9 + tap]);
}

// Layer-1 T pass: block = 32-px row strip x 64 ch; thread = 4 px x 2 ch.
// Wide float4 row loads (deep ILP), u32-packed LDS transpose, full-line NHWC
// writes. 1D grid with bijective XCD chunk swizzle (6272 = 8 x 784).
__global__ __launch_bounds__(256) void tpass1(
    const float* __restrict__ x, const float* __restrict__ wsh,
    u16* __restrict__ th)
{
    __shared__ unsigned TL[32][36];   // [px][ch-pair], stride 36 words

    float wk[9];
#pragma unroll
    for (int k = 0; k < 9; ++k) wk[k] = wsh[k];
    const float wc1 = wk[4] + 1.f;

    const int orig = blockIdx.x;                  // nwg = 6272 = 8*784
    const int swz  = (orig & 7) * 784 + (orig >> 3);
    const int n    = swz / 1568;
    const int rem  = swz - n * 1568;
    const int row  = rem / 7;
    const int strip = rem - row * 7;

    const int tid = threadIdx.x;
    const int qd = tid & 7;          // pixel quad within strip
    const int c2 = tid >> 3;         // channel pair 0..31
    const int w0 = strip * 32 + qd * 4;
    const bool ym = row > 0, yp = row < H_ - 1;
    const bool xm = w0 > 0, xp = w0 + 4 < W_;

    float tq[2][4];
#pragma unroll
    for (int s = 0; s < 2; ++s) {
        const int ch = c2 * 2 + s;
        const float* bp = x + (size_t)n * CHW_ + (size_t)ch * HW_ + row * W_ + w0;

        float m0[4] = {0,0,0,0}, m1[4], m2[4] = {0,0,0,0};
        float l0 = 0.f, r0 = 0.f, l1 = 0.f, r1 = 0.f, l2 = 0.f, r2 = 0.f;
        if (ym) {
            float4 v = *(const float4*)(bp - W_);
            m0[0] = v.x; m0[1] = v.y; m0[2] = v.z; m0[3] = v.w;
            if (xm) l0 = bp[-W_ - 1];
            if (xp) r0 = bp[-W_ + 4];
        }
        {
            float4 v = *(const float4*)bp;
            m1[0] = v.x; m1[1] = v.y; m1[2] = v.z; m1[3] = v.w;
            if (xm) l1 = bp[-1];
            if (xp) r1 = bp[4];
        }
        if (yp) {
            float4 v = *(const float4*)(bp + W_);
            m2[0] = v.x; m2[1] = v.y; m2[2] = v.z; m2[3] = v.w;
            if (xm) l2 = bp[W_ - 1];
            if (xp) r2 = bp[W_ + 4];
        }
#pragma unroll
        for (int j = 0; j < 4; ++j) {
            float a0 = (j == 0) ? l0 : m0[j - 1];
            float a2 = (j == 3) ? r0 : m0[j + 1];
            float b0 = (j == 0) ? l1 : m1[j - 1];
            float b2 = (j == 3) ? r1 : m1[j + 1];
            float c0 = (j == 0) ? l2 : m2[j - 1];
            float c2v = (j == 3) ? r2 : m2[j + 1];
            float t = wc1 * m1[j];
            t = fmaf(wk[0], a0,    t);
            t = fmaf(wk[1], m0[j], t);
            t = fmaf(wk[2], a2,    t);
            t = fmaf(wk[3], b0,    t);
            t = fmaf(wk[5], b2,    t);
            t = fmaf(wk[6], c0,    t);
            t = fmaf(wk[7], m2[j], t);
            t = fmaf(wk[8], c2v,   t);
            tq[s][j] = t;
        }
    }
#pragma unroll
    for (int j = 0; j < 4; ++j)
        TL[qd * 4 + j][c2] = (unsigned)f2bf(tq[0][j]) | ((unsigned)f2bf(tq[1][j]) << 16);
    __syncthreads();

    const int px = tid >> 3, s = tid & 7;
    uint4 v = *(const uint4*)&TL[px][s * 4];
    *(uint4*)(th + (size_t)(n * HW_ + row * W_ + strip * 32 + px) * 64 + s * 8) = v;
}

// Layer-2 T pass on NHWC bf16, v2: thread = 4 consecutive px x 8 ch.
// Per row: 6 uint4 loads (4 px + 2 halo), each value unpacked+normalized ONCE,
// scattered into t[4][8] (static indices). Grid 1568 = 8 x 196, XCD-banded.
__global__ __launch_bounds__(256) void tpass2(
    const u16* __restrict__ inh, const float* __restrict__ wsh,
    const float* __restrict__ raw, const float* __restrict__ gamma,
    const float* __restrict__ beta, u16* __restrict__ th)
{
    __shared__ float SS[128];
    const int tid = threadIdx.x;
    if (tid < 64) {
        const float cnt = (float)(N_ * HW_);
        float mean = raw[tid] / cnt;
        float var  = raw[64 + tid] / cnt - mean * mean;
        float inv  = rsqrtf(var + 1e-5f);
        float scv  = gamma[tid] * inv;
        SS[tid]      = scv;
        SS[64 + tid] = fmaf(-scv, mean, beta[tid]);
    }
    __syncthreads();

    float wk[9];
#pragma unroll
    for (int k = 0; k < 9; ++k) wk[k] = wsh[k];
    const float wc1 = wk[4] + 1.f;

    const int orig = blockIdx.x;                 // 1568 = 8 * 196
    const int swz  = (orig & 7) * 196 + (orig >> 3);
    const int pp4  = swz * 32 + (tid >> 3);      // global 4-px group
    const int s    = tid & 7;
    const int c0   = s * 8;

    float sc[8], sh[8];
#pragma unroll
    for (int j = 0; j < 8; ++j) { sc[j] = SS[c0 + j]; sh[j] = SS[64 + c0 + j]; }

    const int p0  = pp4 * 4;                     // global pixel index (n*HW + pix)
    const int pix = p0 % HW_;
    const int gh  = pix / W_;
    const int gw  = pix - gh * W_;               // multiple of 4
    const bool ym = gh > 0, yp = gh < H_ - 1;
    const bool xm = gw > 0, xp = gw < W_ - 4;

    float t[4][8];
#pragma unroll
    for (int j = 0; j < 4; ++j)
#pragma unroll
        for (int c = 0; c < 8; ++c) t[j][c] = 0.f;

#pragma unroll
    for (int r = 0; r < 3; ++r) {
        if (r == 0 && !ym) continue;
        if (r == 2 && !yp) continue;
        const float w0 = wk[r * 3];
        const float w1 = (r == 1) ? wc1 : wk[r * 3 + 1];
        const float w2 = wk[r * 3 + 2];
        const u16* rb = inh + ((size_t)(p0 + (r - 1) * W_) * 64 + c0);

        uint4 L[6];
        bool lv[6];
#pragma unroll
        for (int m = 0; m < 6; ++m) {
            lv[m] = (m == 0) ? xm : ((m == 5) ? xp : true);
            if (lv[m]) L[m] = *(const uint4*)(rb + (m - 1) * 64);
        }
#pragma unroll
        for (int m = 0; m < 6; ++m) {
            if (!lv[m]) continue;
            unsigned wd_[4] = { L[m].x, L[m].y, L[m].z, L[m].w };
            float val[8];
#pragma unroll
            for (int q = 0; q < 4; ++q) {
                val[2 * q]     = relu_(fmaf(sc[2 * q],     bflo(wd_[q]), sh[2 * q]));
                val[2 * q + 1] = relu_(fmaf(sc[2 * q + 1], bfhi(wd_[q]), sh[2 * q + 1]));
            }
            const int jlo = (m < 2) ? 0 : m - 2;
            const int jhi = (m < 3) ? m : 3;
#pragma unroll
            for (int j = jlo; j <= jhi; ++j) {
                const int dc = m - j;
                const float wgt = (dc == 0) ? w0 : ((dc == 1) ? w1 : w2);
#pragma unroll
                for (int c = 0; c < 8; ++c)
                    t[j][c] = fmaf(wgt, val[c], t[j][c]);
            }
        }
    }

#pragma unroll
    for (int j = 0; j < 4; ++j) {
        uint4 pk;
        pk.x = (unsigned)f2bf(t[j][0]) | ((unsigned)f2bf(t[j][1]) << 16);
        pk.y = (unsigned)f2bf(t[j][2]) | ((unsigned)f2bf(t[j][3]) << 16);
        pk.z = (unsigned)f2bf(t[j][4]) | ((unsigned)f2bf(t[j][5]) << 16);
        pk.w = (unsigned)f2bf(t[j][6]) | ((unsigned)f2bf(t[j][7]) << 16);
        *(uint4*)(th + (size_t)(p0 + j) * 64 + c0) = pk;
    }
}

// Dense 3x3 conv as implicit GEMM over NHWC bf16 T (R10/R14-benched body:
// mf-outer loop, B[18] hoisted, staging via global_load_lds with source-side
// XOR swizzle, staging issued first; TW=32 x TH=8 tile; launch_bounds(256,3)).
// This body is a verified local optimum: 6 restructure attempts all regressed
// (spill or serialization). Do not modify.
// LAYER 1: resid = x fp32 NCHW, dst = o1h bf16 NHWC.
// LAYER 2: resid = relu(bn1(o1h)), stats from raw1 in-block; dst = o2 fp32 NCHW.
template<int LAYER>
__global__ __launch_bounds__(256, 3) void conv_mfma(
    const u16* __restrict__ th, const u16* __restrict__ wpre,
    const float* __restrict__ bd,
    const float* __restrict__ rawin, const float* __restrict__ gamma,
    const float* __restrict__ beta,
    const float* __restrict__ resx, const u16* __restrict__ reso,
    const u16* __restrict__ zp,
    u16* __restrict__ dsth, float* __restrict__ dstf,
    float* __restrict__ raw)
{
    __shared__ __align__(16) char TlB[340 * 128];   // 43520 B
    __shared__ float Sr[128];
    __shared__ float SS[128];

    const int tid = threadIdx.x;
    // XCD band swizzle: 784 = 8 * 98; XCD k owns a contiguous 112-row band
    // of image n=k/2 (matches tpass banding for cross-kernel L2 reuse).
    const int orig = blockIdx.x;
    const int swz  = (orig & 7) * 98 + (orig >> 3);
    const int wx   = swz % 7;
    const int t_   = swz / 7;            // n*28 + hy
    const int n    = t_ / 28;
    const int hy   = t_ - n * 28;
    const int h0 = hy * 8, w0 = wx * 32;

    const int lane = tid & 63, wg = tid >> 6;
    const int l15 = lane & 15, lg = lane >> 4;
    const int o = wg * 16 + l15;

    // Stage T halo (34x10 pixels x 128B) via global_load_lds FIRST:
    // LDS dest linear (wave base + lane*16); XOR swizzle applied to the
    // GLOBAL source address (involution; read side unchanged). OOB -> zero page.
#pragma unroll
    for (int it = 0; it < 11; ++it) {
        const int f = it * 256 + tid;
        if (f < 2720) {
            const int pix = f >> 3, s = f & 7;
            const int hr = pix / 34, wc = pix - hr * 34;
            const int gh = h0 - 1 + hr, gw = w0 - 1 + wc;
            const u16* src = zp;
            if ((unsigned)gh < (unsigned)H_ && (unsigned)gw < (unsigned)W_)
                src = th + (size_t)(n * HW_ + gh * W_ + gw) * 64 +
                      ((s * 8) ^ ((pix & 7) << 3));
            gl_lds16(src, TlB + (size_t)(it * 256 + (tid & 192)) * 16);
        }
    }

    if (LAYER == 2 && tid < 64) {
        const float cnt = (float)(N_ * HW_);
        float mean = rawin[tid] / cnt;
        float var  = rawin[64 + tid] / cnt - mean * mean;
        float inv  = rsqrtf(var + 1e-5f);
        float scv  = gamma[tid] * inv;
        SS[tid]      = scv;
        SS[64 + tid] = fmaf(-scv, mean, beta[tid]);
    }

    // B fragments: [tap][cc] -> 18 x bf16x8 in registers (L2-cached source),
    // issued in the staging DMA's shadow.
    bf8 B[18];
#pragma unroll
    for (int tap = 0; tap < 9; ++tap)
#pragma unroll
        for (int cc = 0; cc < 2; ++cc)
            B[tap * 2 + cc] = *(const bf8*)(wpre + ((tap * 64 + o) * 64 + cc * 32 + lg * 8));

    __syncthreads();

    f4v acc[16];
#pragma unroll
    for (int mf = 0; mf < 16; ++mf) acc[mf] = (f4v){0.f, 0.f, 0.f, 0.f};

#pragma unroll
    for (int mf = 0; mf < 16; ++mf) {
        const int h = mf >> 1, half = mf & 1;
#pragma unroll
        for (int tap = 0; tap < 9; ++tap) {
            const int dr = tap / 3, dc = tap - dr * 3;
            const int hp = (h + dr) * 34 + half * 16 + dc + l15;
#pragma unroll
            for (int cc = 0; cc < 2; ++cc) {
                const bf8 A = *(const bf8*)(TlB + hp * 128 +
                                            ((cc * 64 + lg * 16) ^ ((hp & 7) << 4)));
                acc[mf] = __builtin_amdgcn_mfma_f32_16x16x32_bf16(
                    A, B[tap * 2 + cc], acc[mf], 0, 0, 0);
            }
        }
    }

    // Epilogue: bias + residual + store + per-channel stats
    const float bv = bd[o];
    float scO = 1.f, shO = 0.f;
    if (LAYER == 2) { scO = SS[o]; shO = SS[64 + o]; }
    float ps1 = 0.f, ps2 = 0.f;
#pragma unroll
    for (int mf = 0; mf < 16; ++mf) {
        const int h = h0 + (mf >> 1);
        const int w = w0 + (mf & 1) * 16 + lg * 4;
        const int ppix = n * HW_ + h * W_ + w;
        float vo[4];
        if (LAYER == 1) {
            const float4 rx = *(const float4*)(resx + (size_t)n * CHW_ + (size_t)o * HW_ + h * W_ + w);
            vo[0] = acc[mf][0] + bv + rx.x;
            vo[1] = acc[mf][1] + bv + rx.y;
            vo[2] = acc[mf][2] + bv + rx.z;
            vo[3] = acc[mf][3] + bv + rx.w;
#pragma unroll
            for (int r = 0; r < 4; ++r)
                dsth[(size_t)(ppix + r) * 64 + o] = f2bf(vo[r]);
        } else {
#pragma unroll
            for (int r = 0; r < 4; ++r) {
                float n1 = relu_(fmaf(scO, bf2f(reso[(size_t)(ppix + r) * 64 + o]), shO));
                vo[r] = acc[mf][r] + bv + n1;
            }
            float4 st = { vo[0], vo[1], vo[2], vo[3] };
            *(float4*)(dstf + (size_t)n * CHW_ + (size_t)o * HW_ + h * W_ + w) = st;
        }
        ps1 += (vo[0] + vo[1]) + (vo[2] + vo[3]);
        ps2 += fmaf(vo[0], vo[0], fmaf(vo[1], vo[1], fmaf(vo[2], vo[2], vo[3] * vo[3])));
    }
    ps1 += __shfl_xor(ps1, 16); ps1 += __shfl_xor(ps1, 32);
    ps2 += __shfl_xor(ps2, 16); ps2 += __shfl_xor(ps2, 32);
    if (lane < 16) { Sr[o] = ps1; Sr[64 + o] = ps2; }
    __syncthreads();
    if (tid < 128) atomicAdd(&raw[tid], Sr[tid]);
}

// io = relu(bn2(io)) + x, bn2 scale/shift computed in-block from raw2 sums.
__global__ __launch_bounds__(256) void final_k(
    float4* io, const float* __restrict__ raw, const float* __restrict__ gamma,
    const float* __restrict__ beta, const float4* __restrict__ x)
{
    __shared__ float SS[128];
    if (threadIdx.x < 64) {
        const int c = threadIdx.x;
        const float cnt = (float)(N_ * HW_);
        float mean = raw[c] / cnt;
        float var  = raw[64 + c] / cnt - mean * mean;
        float inv  = rsqrtf(var + 1e-5f);
        float scv  = gamma[c] * inv;
        SS[c]      = scv;
        SS[64 + c] = fmaf(-scv, mean, beta[c]);
    }
    __syncthreads();

    const int nq = TOT_ / 4;
    for (int i = blockIdx.x * 256 + threadIdx.x; i < nq; i += gridDim.x * 256) {
        int c = (i / (HW_ / 4)) & 63;
        float sc = SS[c], sh = SS[64 + c];
        float4 v = io[i], xx = x[i];
        float4 rr;
        rr.x = relu_(fmaf(sc, v.x, sh)) + xx.x;
        rr.y = relu_(fmaf(sc, v.y, sh)) + xx.y;
        rr.z = relu_(fmaf(sc, v.z, sh)) + xx.z;
        rr.w = relu_(fmaf(sc, v.w, sh)) + xx.w;
        io[i] = rr;
    }
}

extern "C" void kernel_launch(void* const* d_in, const int* in_sizes, int n_in,
                              void* d_out, int out_size, void* d_ws, size_t ws_size,
                              hipStream_t stream)
{
    const float* x    = (const float*)d_in[0];
    const float* wsh1 = (const float*)d_in[1];
    const float* wd1  = (const float*)d_in[2];
    const float* bd1  = (const float*)d_in[3];
    const float* wsh2 = (const float*)d_in[4];
    const float* wd2  = (const float*)d_in[5];
    const float* bd2  = (const float*)d_in[6];
    const float* g1   = (const float*)d_in[7];
    const float* be1  = (const float*)d_in[8];
    const float* g2   = (const float*)d_in[9];
    const float* be2  = (const float*)d_in[10];

    float* out = (float*)d_out;
    u16* Th   = (u16*)d_ws;            // TOT_ u16  (T tensor NHWC, both layers)
    u16* O1h  = Th + TOT_;             // TOT_ u16  (o1 bf16 NHWC)
    u16* Wpre = O1h + TOT_;            // 73728 u16
    float* raw1 = (float*)(Wpre + 73728);  // 128
    float* raw2 = raw1 + 128;              // 128
    u16*   zp   = (u16*)(raw2 + 128);      // 64 u16 zero page (OOB halo src)

    // zero raw1+raw2+zp in one async memset (graph-capture safe)
    hipMemsetAsync(raw1, 0, 256 * sizeof(float) + 128, stream);
    prep_w<<<288, 256, 0, stream>>>(wd1, wd2, Wpre);

    const int tgrid = N_ * H_ * 7;     // 6272 = 8 * 784 (swizzle-divisible)
    const int cgrid = 784;             // 8 * 98, 1D XCD-banded
    const int t2grid = 1568;           // 8 * 196, XCD-banded (matches conv bands)

    // T1 = dw(x) + x  (NHWC bf16, fused transpose from fp32 NCHW)
    tpass1<<<tgrid, 256, 0, stream>>>(x, wsh1, Th);
    // o1 = conv(T1) + b1 + x -> o1h (bf16 NHWC); raw1 stats
    conv_mfma<1><<<cgrid, 256, 0, stream>>>(Th, Wpre, bd1,
                                            nullptr, nullptr, nullptr,
                                            x, nullptr, zp, O1h, nullptr, raw1);
    // T2 = dw(n1) + n1, n1 = relu(bn1(o1h)); bn1 stats folded in
    tpass2<<<t2grid, 256, 0, stream>>>(O1h, wsh2, raw1, g1, be1, Th);
    // o2 = conv(T2) + b2 + n1 -> d_out (fp32 NCHW); raw2 stats
    conv_mfma<2><<<cgrid, 256, 0, stream>>>(Th, Wpre + 36864, bd2,
                                            raw1, g1, be1,
                                            nullptr, O1h, zp, nullptr, out, raw2);
    // out = relu(bn2(o2)) + x; bn2 stats folded in
    final_k<<<2048, 256, 0, stream>>>((float4*)out, raw2, g2, be2, (const float4*)x);
}

// Round 17
// 156.611 us; speedup vs baseline: 1.4027x; 1.0422x over previous
//
#include <hip/hip_runtime.h>

#define N_ 4
#define C_ 64
#define H_ 224
#define W_ 224
#define HW_ (H_ * W_)        /* 50176 */
#define CHW_ (C_ * HW_)      /* 3211264 */
#define TOT_ (N_ * CHW_)     /* 12845056 */

typedef __bf16 bf8 __attribute__((ext_vector_type(8)));
typedef float  f4v __attribute__((ext_vector_type(4)));
typedef unsigned short u16;

__device__ __forceinline__ float relu_(float v) { return fmaxf(v, 0.f); }
__device__ __forceinline__ u16 f2bf(float f) {
    unsigned u = __builtin_bit_cast(unsigned, f);
    return (u16)((u + 0x7FFFu + ((u >> 16) & 1u)) >> 16);
}
__device__ __forceinline__ float bf2f(u16 h) {
    unsigned u = ((unsigned)h) << 16;
    return __builtin_bit_cast(float, u);
}
__device__ __forceinline__ float bflo(unsigned u) {
    return __builtin_bit_cast(float, u << 16);
}
__device__ __forceinline__ float bfhi(unsigned u) {
    return __builtin_bit_cast(float, u & 0xFFFF0000u);
}

// async 16B global->LDS (LDS dest = wave-uniform base + lane*16)
__device__ __forceinline__ void gl_lds16(const void* g, void* l) {
    __builtin_amdgcn_global_load_lds(
        (const __attribute__((address_space(1))) void*)g,
        (__attribute__((address_space(3))) void*)l, 16, 0, 0);
}

// Layer-1 T pass: block = 32-px row strip x 64 ch; thread = 4 px x 2 ch.
// Wide float4 row loads (deep ILP), u32-packed LDS transpose, full-line NHWC
// writes. 1D grid with bijective XCD chunk swizzle (6272 = 8 x 784).
// FUSED PROLOGUE: blocks 0..287 also convert wd1/wd2 -> Wpre
// (Wpre[sel][tap][o][k] bf16 <- wd[o][k][tap]); block 288 zeroes
// raw1+raw2+zp (288 u32, contiguous). Same-stream ordering makes these
// ready before conv1 launches.
__global__ __launch_bounds__(256) void tpass1(
    const float* __restrict__ x, const float* __restrict__ wsh,
    const float* __restrict__ wd1, const float* __restrict__ wd2,
    u16* __restrict__ wpre, unsigned* __restrict__ rawz,
    u16* __restrict__ th)
{
    __shared__ unsigned TL[32][36];   // [px][ch-pair], stride 36 words

    const int tid = threadIdx.x;
    const int orig = blockIdx.x;                  // nwg = 6272 = 8*784

    // ---- fused prep_w (blocks 0..287) + raw/zp zeroing (block 288) ----
    if (orig < 288) {
        int i = orig * 256 + tid;
        if (i < 73728) {
            int sel = i >= 36864;
            int r   = i - sel * 36864;
            int tap = r >> 12;
            int r2  = r & 4095;
            int o   = r2 >> 6, k = r2 & 63;
            const float* ws = sel ? wd2 : wd1;
            wpre[i] = f2bf(ws[o * 576 + k * 9 + tap]);
        }
    } else if (orig == 288) {
        for (int j = tid; j < 288; j += 256) rawz[j] = 0u;
    }

    float wk[9];
#pragma unroll
    for (int k = 0; k < 9; ++k) wk[k] = wsh[k];
    const float wc1 = wk[4] + 1.f;

    const int swz  = (orig & 7) * 784 + (orig >> 3);
    const int n    = swz / 1568;
    const int rem  = swz - n * 1568;
    const int row  = rem / 7;
    const int strip = rem - row * 7;

    const int qd = tid & 7;          // pixel quad within strip
    const int c2 = tid >> 3;         // channel pair 0..31
    const int w0 = strip * 32 + qd * 4;
    const bool ym = row > 0, yp = row < H_ - 1;
    const bool xm = w0 > 0, xp = w0 + 4 < W_;

    float tq[2][4];
#pragma unroll
    for (int s = 0; s < 2; ++s) {
        const int ch = c2 * 2 + s;
        const float* bp = x + (size_t)n * CHW_ + (size_t)ch * HW_ + row * W_ + w0;

        float m0[4] = {0,0,0,0}, m1[4], m2[4] = {0,0,0,0};
        float l0 = 0.f, r0 = 0.f, l1 = 0.f, r1 = 0.f, l2 = 0.f, r2 = 0.f;
        if (ym) {
            float4 v = *(const float4*)(bp - W_);
            m0[0] = v.x; m0[1] = v.y; m0[2] = v.z; m0[3] = v.w;
            if (xm) l0 = bp[-W_ - 1];
            if (xp) r0 = bp[-W_ + 4];
        }
        {
            float4 v = *(const float4*)bp;
            m1[0] = v.x; m1[1] = v.y; m1[2] = v.z; m1[3] = v.w;
            if (xm) l1 = bp[-1];
            if (xp) r1 = bp[4];
        }
        if (yp) {
            float4 v = *(const float4*)(bp + W_);
            m2[0] = v.x; m2[1] = v.y; m2[2] = v.z; m2[3] = v.w;
            if (xm) l2 = bp[W_ - 1];
            if (xp) r2 = bp[W_ + 4];
        }
#pragma unroll
        for (int j = 0; j < 4; ++j) {
            float a0 = (j == 0) ? l0 : m0[j - 1];
            float a2 = (j == 3) ? r0 : m0[j + 1];
            float b0 = (j == 0) ? l1 : m1[j - 1];
            float b2 = (j == 3) ? r1 : m1[j + 1];
            float c0 = (j == 0) ? l2 : m2[j - 1];
            float c2v = (j == 3) ? r2 : m2[j + 1];
            float t = wc1 * m1[j];
            t = fmaf(wk[0], a0,    t);
            t = fmaf(wk[1], m0[j], t);
            t = fmaf(wk[2], a2,    t);
            t = fmaf(wk[3], b0,    t);
            t = fmaf(wk[5], b2,    t);
            t = fmaf(wk[6], c0,    t);
            t = fmaf(wk[7], m2[j], t);
            t = fmaf(wk[8], c2v,   t);
            tq[s][j] = t;
        }
    }
#pragma unroll
    for (int j = 0; j < 4; ++j)
        TL[qd * 4 + j][c2] = (unsigned)f2bf(tq[0][j]) | ((unsigned)f2bf(tq[1][j]) << 16);
    __syncthreads();

    const int px = tid >> 3, s = tid & 7;
    uint4 v = *(const uint4*)&TL[px][s * 4];
    *(uint4*)(th + (size_t)(n * HW_ + row * W_ + strip * 32 + px) * 64 + s * 8) = v;
}

// Layer-2 T pass on NHWC bf16, v2: thread = 4 consecutive px x 8 ch.
// Per row: 6 uint4 loads (4 px + 2 halo), each value unpacked+normalized ONCE,
// scattered into t[4][8] (static indices). Grid 1568 = 8 x 196, XCD-banded.
__global__ __launch_bounds__(256) void tpass2(
    const u16* __restrict__ inh, const float* __restrict__ wsh,
    const float* __restrict__ raw, const float* __restrict__ gamma,
    const float* __restrict__ beta, u16* __restrict__ th)
{
    __shared__ float SS[128];
    const int tid = threadIdx.x;
    if (tid < 64) {
        const float cnt = (float)(N_ * HW_);
        float mean = raw[tid] / cnt;
        float var  = raw[64 + tid] / cnt - mean * mean;
        float inv  = rsqrtf(var + 1e-5f);
        float scv  = gamma[tid] * inv;
        SS[tid]      = scv;
        SS[64 + tid] = fmaf(-scv, mean, beta[tid]);
    }
    __syncthreads();

    float wk[9];
#pragma unroll
    for (int k = 0; k < 9; ++k) wk[k] = wsh[k];
    const float wc1 = wk[4] + 1.f;

    const int orig = blockIdx.x;                 // 1568 = 8 * 196
    const int swz  = (orig & 7) * 196 + (orig >> 3);
    const int pp4  = swz * 32 + (tid >> 3);      // global 4-px group
    const int s    = tid & 7;
    const int c0   = s * 8;

    float sc[8], sh[8];
#pragma unroll
    for (int j = 0; j < 8; ++j) { sc[j] = SS[c0 + j]; sh[j] = SS[64 + c0 + j]; }

    const int p0  = pp4 * 4;                     // global pixel index (n*HW + pix)
    const int pix = p0 % HW_;
    const int gh  = pix / W_;
    const int gw  = pix - gh * W_;               // multiple of 4
    const bool ym = gh > 0, yp = gh < H_ - 1;
    const bool xm = gw > 0, xp = gw < W_ - 4;

    float t[4][8];
#pragma unroll
    for (int j = 0; j < 4; ++j)
#pragma unroll
        for (int c = 0; c < 8; ++c) t[j][c] = 0.f;

#pragma unroll
    for (int r = 0; r < 3; ++r) {
        if (r == 0 && !ym) continue;
        if (r == 2 && !yp) continue;
        const float w0 = wk[r * 3];
        const float w1 = (r == 1) ? wc1 : wk[r * 3 + 1];
        const float w2 = wk[r * 3 + 2];
        const u16* rb = inh + ((size_t)(p0 + (r - 1) * W_) * 64 + c0);

        uint4 L[6];
        bool lv[6];
#pragma unroll
        for (int m = 0; m < 6; ++m) {
            lv[m] = (m == 0) ? xm : ((m == 5) ? xp : true);
            if (lv[m]) L[m] = *(const uint4*)(rb + (m - 1) * 64);
        }
#pragma unroll
        for (int m = 0; m < 6; ++m) {
            if (!lv[m]) continue;
            unsigned wd_[4] = { L[m].x, L[m].y, L[m].z, L[m].w };
            float val[8];
#pragma unroll
            for (int q = 0; q < 4; ++q) {
                val[2 * q]     = relu_(fmaf(sc[2 * q],     bflo(wd_[q]), sh[2 * q]));
                val[2 * q + 1] = relu_(fmaf(sc[2 * q + 1], bfhi(wd_[q]), sh[2 * q + 1]));
            }
            const int jlo = (m < 2) ? 0 : m - 2;
            const int jhi = (m < 3) ? m : 3;
#pragma unroll
            for (int j = jlo; j <= jhi; ++j) {
                const int dc = m - j;
                const float wgt = (dc == 0) ? w0 : ((dc == 1) ? w1 : w2);
#pragma unroll
                for (int c = 0; c < 8; ++c)
                    t[j][c] = fmaf(wgt, val[c], t[j][c]);
            }
        }
    }

#pragma unroll
    for (int j = 0; j < 4; ++j) {
        uint4 pk;
        pk.x = (unsigned)f2bf(t[j][0]) | ((unsigned)f2bf(t[j][1]) << 16);
        pk.y = (unsigned)f2bf(t[j][2]) | ((unsigned)f2bf(t[j][3]) << 16);
        pk.z = (unsigned)f2bf(t[j][4]) | ((unsigned)f2bf(t[j][5]) << 16);
        pk.w = (unsigned)f2bf(t[j][6]) | ((unsigned)f2bf(t[j][7]) << 16);
        *(uint4*)(th + (size_t)(p0 + j) * 64 + c0) = pk;
    }
}

// Dense 3x3 conv as implicit GEMM over NHWC bf16 T (R10/R14-benched body:
// mf-outer loop, B[18] hoisted, staging via global_load_lds with source-side
// XOR swizzle, staging issued first; TW=32 x TH=8 tile; launch_bounds(256,3)).
// This body is a verified local optimum: 6 restructure attempts all regressed
// (spill or serialization). Do not modify.
// LAYER 1: resid = x fp32 NCHW, dst = o1h bf16 NHWC.
// LAYER 2: resid = relu(bn1(o1h)), stats from raw1 in-block; dst = o2 fp32 NCHW.
template<int LAYER>
__global__ __launch_bounds__(256, 3) void conv_mfma(
    const u16* __restrict__ th, const u16* __restrict__ wpre,
    const float* __restrict__ bd,
    const float* __restrict__ rawin, const float* __restrict__ gamma,
    const float* __restrict__ beta,
    const float* __restrict__ resx, const u16* __restrict__ reso,
    const u16* __restrict__ zp,
    u16* __restrict__ dsth, float* __restrict__ dstf,
    float* __restrict__ raw)
{
    __shared__ __align__(16) char TlB[340 * 128];   // 43520 B
    __shared__ float Sr[128];
    __shared__ float SS[128];

    const int tid = threadIdx.x;
    // XCD band swizzle: 784 = 8 * 98; XCD k owns a contiguous 112-row band
    // of image n=k/2 (matches tpass banding for cross-kernel L2 reuse).
    const int orig = blockIdx.x;
    const int swz  = (orig & 7) * 98 + (orig >> 3);
    const int wx   = swz % 7;
    const int t_   = swz / 7;            // n*28 + hy
    const int n    = t_ / 28;
    const int hy   = t_ - n * 28;
    const int h0 = hy * 8, w0 = wx * 32;

    const int lane = tid & 63, wg = tid >> 6;
    const int l15 = lane & 15, lg = lane >> 4;
    const int o = wg * 16 + l15;

    // Stage T halo (34x10 pixels x 128B) via global_load_lds FIRST:
    // LDS dest linear (wave base + lane*16); XOR swizzle applied to the
    // GLOBAL source address (involution; read side unchanged). OOB -> zero page.
#pragma unroll
    for (int it = 0; it < 11; ++it) {
        const int f = it * 256 + tid;
        if (f < 2720) {
            const int pix = f >> 3, s = f & 7;
            const int hr = pix / 34, wc = pix - hr * 34;
            const int gh = h0 - 1 + hr, gw = w0 - 1 + wc;
            const u16* src = zp;
            if ((unsigned)gh < (unsigned)H_ && (unsigned)gw < (unsigned)W_)
                src = th + (size_t)(n * HW_ + gh * W_ + gw) * 64 +
                      ((s * 8) ^ ((pix & 7) << 3));
            gl_lds16(src, TlB + (size_t)(it * 256 + (tid & 192)) * 16);
        }
    }

    if (LAYER == 2 && tid < 64) {
        const float cnt = (float)(N_ * HW_);
        float mean = rawin[tid] / cnt;
        float var  = rawin[64 + tid] / cnt - mean * mean;
        float inv  = rsqrtf(var + 1e-5f);
        float scv  = gamma[tid] * inv;
        SS[tid]      = scv;
        SS[64 + tid] = fmaf(-scv, mean, beta[tid]);
    }

    // B fragments: [tap][cc] -> 18 x bf16x8 in registers (L2-cached source),
    // issued in the staging DMA's shadow.
    bf8 B[18];
#pragma unroll
    for (int tap = 0; tap < 9; ++tap)
#pragma unroll
        for (int cc = 0; cc < 2; ++cc)
            B[tap * 2 + cc] = *(const bf8*)(wpre + ((tap * 64 + o) * 64 + cc * 32 + lg * 8));

    __syncthreads();

    f4v acc[16];
#pragma unroll
    for (int mf = 0; mf < 16; ++mf) acc[mf] = (f4v){0.f, 0.f, 0.f, 0.f};

#pragma unroll
    for (int mf = 0; mf < 16; ++mf) {
        const int h = mf >> 1, half = mf & 1;
#pragma unroll
        for (int tap = 0; tap < 9; ++tap) {
            const int dr = tap / 3, dc = tap - dr * 3;
            const int hp = (h + dr) * 34 + half * 16 + dc + l15;
#pragma unroll
            for (int cc = 0; cc < 2; ++cc) {
                const bf8 A = *(const bf8*)(TlB + hp * 128 +
                                            ((cc * 64 + lg * 16) ^ ((hp & 7) << 4)));
                acc[mf] = __builtin_amdgcn_mfma_f32_16x16x32_bf16(
                    A, B[tap * 2 + cc], acc[mf], 0, 0, 0);
            }
        }
    }

    // Epilogue: bias + residual + store + per-channel stats
    const float bv = bd[o];
    float scO = 1.f, shO = 0.f;
    if (LAYER == 2) { scO = SS[o]; shO = SS[64 + o]; }
    float ps1 = 0.f, ps2 = 0.f;
#pragma unroll
    for (int mf = 0; mf < 16; ++mf) {
        const int h = h0 + (mf >> 1);
        const int w = w0 + (mf & 1) * 16 + lg * 4;
        const int ppix = n * HW_ + h * W_ + w;
        float vo[4];
        if (LAYER == 1) {
            const float4 rx = *(const float4*)(resx + (size_t)n * CHW_ + (size_t)o * HW_ + h * W_ + w);
            vo[0] = acc[mf][0] + bv + rx.x;
            vo[1] = acc[mf][1] + bv + rx.y;
            vo[2] = acc[mf][2] + bv + rx.z;
            vo[3] = acc[mf][3] + bv + rx.w;
#pragma unroll
            for (int r = 0; r < 4; ++r)
                dsth[(size_t)(ppix + r) * 64 + o] = f2bf(vo[r]);
        } else {
#pragma unroll
            for (int r = 0; r < 4; ++r) {
                float n1 = relu_(fmaf(scO, bf2f(reso[(size_t)(ppix + r) * 64 + o]), shO));
                vo[r] = acc[mf][r] + bv + n1;
            }
            float4 st = { vo[0], vo[1], vo[2], vo[3] };
            *(float4*)(dstf + (size_t)n * CHW_ + (size_t)o * HW_ + h * W_ + w) = st;
        }
        ps1 += (vo[0] + vo[1]) + (vo[2] + vo[3]);
        ps2 += fmaf(vo[0], vo[0], fmaf(vo[1], vo[1], fmaf(vo[2], vo[2], vo[3] * vo[3])));
    }
    ps1 += __shfl_xor(ps1, 16); ps1 += __shfl_xor(ps1, 32);
    ps2 += __shfl_xor(ps2, 16); ps2 += __shfl_xor(ps2, 32);
    if (lane < 16) { Sr[o] = ps1; Sr[64 + o] = ps2; }
    __syncthreads();
    if (tid < 128) atomicAdd(&raw[tid], Sr[tid]);
}

// io = relu(bn2(io)) + x, bn2 scale/shift computed in-block from raw2 sums.
__global__ __launch_bounds__(256) void final_k(
    float4* io, const float* __restrict__ raw, const float* __restrict__ gamma,
    const float* __restrict__ beta, const float4* __restrict__ x)
{
    __shared__ float SS[128];
    if (threadIdx.x < 64) {
        const int c = threadIdx.x;
        const float cnt = (float)(N_ * HW_);
        float mean = raw[c] / cnt;
        float var  = raw[64 + c] / cnt - mean * mean;
        float inv  = rsqrtf(var + 1e-5f);
        float scv  = gamma[c] * inv;
        SS[c]      = scv;
        SS[64 + c] = fmaf(-scv, mean, beta[c]);
    }
    __syncthreads();

    const int nq = TOT_ / 4;
    for (int i = blockIdx.x * 256 + threadIdx.x; i < nq; i += gridDim.x * 256) {
        int c = (i / (HW_ / 4)) & 63;
        float sc = SS[c], sh = SS[64 + c];
        float4 v = io[i], xx = x[i];
        float4 rr;
        rr.x = relu_(fmaf(sc, v.x, sh)) + xx.x;
        rr.y = relu_(fmaf(sc, v.y, sh)) + xx.y;
        rr.z = relu_(fmaf(sc, v.z, sh)) + xx.z;
        rr.w = relu_(fmaf(sc, v.w, sh)) + xx.w;
        io[i] = rr;
    }
}

extern "C" void kernel_launch(void* const* d_in, const int* in_sizes, int n_in,
                              void* d_out, int out_size, void* d_ws, size_t ws_size,
                              hipStream_t stream)
{
    const float* x    = (const float*)d_in[0];
    const float* wsh1 = (const float*)d_in[1];
    const float* wd1  = (const float*)d_in[2];
    const float* bd1  = (const float*)d_in[3];
    const float* wsh2 = (const float*)d_in[4];
    const float* wd2  = (const float*)d_in[5];
    const float* bd2  = (const float*)d_in[6];
    const float* g1   = (const float*)d_in[7];
    const float* be1  = (const float*)d_in[8];
    const float* g2   = (const float*)d_in[9];
    const float* be2  = (const float*)d_in[10];

    float* out = (float*)d_out;
    u16* Th   = (u16*)d_ws;            // TOT_ u16  (T tensor NHWC, both layers)
    u16* O1h  = Th + TOT_;             // TOT_ u16  (o1 bf16 NHWC)
    u16* Wpre = O1h + TOT_;            // 73728 u16
    float* raw1 = (float*)(Wpre + 73728);  // 128
    float* raw2 = raw1 + 128;              // 128
    u16*   zp   = (u16*)(raw2 + 128);      // 64 u16 zero page (OOB halo src)

    const int tgrid = N_ * H_ * 7;     // 6272 = 8 * 784 (swizzle-divisible)
    const int cgrid = 784;             // 8 * 98, 1D XCD-banded
    const int t2grid = 1568;           // 8 * 196, XCD-banded (matches conv bands)

    // T1 = dw(x) + x (NHWC bf16) + fused weight prep + raw/zp zeroing
    tpass1<<<tgrid, 256, 0, stream>>>(x, wsh1, wd1, wd2, Wpre,
                                      (unsigned*)raw1, Th);
    // o1 = conv(T1) + b1 + x -> o1h (bf16 NHWC); raw1 stats
    conv_mfma<1><<<cgrid, 256, 0, stream>>>(Th, Wpre, bd1,
                                            nullptr, nullptr, nullptr,
                                            x, nullptr, zp, O1h, nullptr, raw1);
    // T2 = dw(n1) + n1, n1 = relu(bn1(o1h)); bn1 stats folded in
    tpass2<<<t2grid, 256, 0, stream>>>(O1h, wsh2, raw1, g1, be1, Th);
    // o2 = conv(T2) + b2 + n1 -> d_out (fp32 NCHW); raw2 stats
    conv_mfma<2><<<cgrid, 256, 0, stream>>>(Th, Wpre + 36864, bd2,
                                            raw1, g1, be1,
                                            nullptr, O1h, zp, nullptr, out, raw2);
    // out = relu(bn2(o2)) + x; bn2 stats folded in
    final_k<<<2048, 256, 0, stream>>>((float4*)out, raw2, g2, be2, (const float4*)x);
}